// Round 4
// baseline (524.024 us; speedup 1.0000x reference)
//
#include <hip/hip_runtime.h>
#include <hip/hip_bf16.h>
#include <math.h>

#define B_ 8
#define T_ 8192
#define V_ 256
#define EB_ 64
#define E_ 64
#define H_ 512
#define SS_ 32
#define FEATP_ 192   // padded feature dim (real 132, zero-padded to 192 = 3*64 for BK=64 core)
#define NCH_ 256
#define CHUNK_ 32

typedef __attribute__((ext_vector_type(8))) short bf8;     // 8 bf16 = 4 VGPRs (MFMA A/B frag)
typedef __attribute__((ext_vector_type(16))) float accv;   // MFMA 32x32 C/D frag

#define AS1(p) (__attribute__((address_space(1))) void*)(void*)(p)
#define AS3(p) (__attribute__((address_space(3))) void*)(void*)(p)

__device__ __forceinline__ float silu_f(float x) { return x / (1.0f + expf(-x)); }
__device__ __forceinline__ float sigm_f(float x) { return 1.0f / (1.0f + expf(-x)); }
__device__ __forceinline__ float bf2f(__hip_bfloat16 v) { return __bfloat162float(v); }
__device__ __forceinline__ __hip_bfloat16 f2bf(float v) { return __float2bfloat16(v); }
__device__ __forceinline__ float us2f(ushort u) {
    union { float f; unsigned int u32; } c; c.u32 = ((unsigned int)u) << 16; return c.f;
}
__device__ __forceinline__ ushort f2us(float v) {
    __hip_bfloat16 t = __float2bfloat16(v);
    return *reinterpret_cast<ushort*>(&t);
}

#define CD_ROW(r, lane) (((r) & 3) + 8 * ((r) >> 2) + 4 * ((lane) >> 5))

// bijective XCD-chunk swizzle (nwg % 8 == 0): neighbor wgids land on same XCD L2
__device__ __forceinline__ int xcd_swz(int bid, int nwg) {
    return (bid & 7) * (nwg >> 3) + (bid >> 3);
}

// ===================== 256x256 MFMA core (used by k_win256) =====================
template <int KD>
__device__ __forceinline__ void mm256(const ushort* __restrict__ Ab,
                                      const ushort* __restrict__ Bb,
                                      int m0, int n0, accv (&acc)[4][2]) {
    constexpr int NT = KD / 64;
    __shared__ __align__(1024) ushort lA[32768];   // 64 KiB: 2 slots x [256][64]
    __shared__ __align__(1024) ushort lB[32768];   // 64 KiB
    const int tid  = threadIdx.x;
    const int lane = tid & 63;
    const int w    = tid >> 6;
    const int wm   = w >> 2, wn = w & 3;

    const int lrow = lane >> 3;                 // 0..7
    const int lcg  = (lane & 7) ^ lrow;         // swizzled source chunk
    const ushort* gA = Ab + (size_t)(m0 + w * 32 + lrow) * KD + lcg * 8;
    const ushort* gB = Bb + (size_t)(n0 + w * 32 + lrow) * KD + lcg * 8;
    const int dstw = w * 2048;

    const int swz  = (lane & 7) << 4;           // bytes
    const int kh16 = (lane >> 5) * 16;          // bytes
    int oK[4];
#pragma unroll
    for (int ks = 0; ks < 4; ks++) oK[ks] = ((ks * 32 + kh16) ^ swz) >> 1;  // ushorts
    const int rowA = (128 * wm + (lane & 31)) * 64;
    const int rowB = (64 * wn + (lane & 31)) * 64;

#define STG8(slot, kt)                                                                             \
    do {                                                                                           \
        __builtin_amdgcn_global_load_lds(AS1(gA + (kt)),                                           \
                                         AS3(&lA[(slot) * 16384 + dstw + 0 * 512]), 16, 0, 0);     \
        __builtin_amdgcn_global_load_lds(AS1(gB + (kt)),                                           \
                                         AS3(&lB[(slot) * 16384 + dstw + 0 * 512]), 16, 0, 0);     \
        __builtin_amdgcn_global_load_lds(AS1(gA + (size_t)8 * KD + (kt)),                          \
                                         AS3(&lA[(slot) * 16384 + dstw + 1 * 512]), 16, 0, 0);     \
        __builtin_amdgcn_global_load_lds(AS1(gB + (size_t)8 * KD + (kt)),                          \
                                         AS3(&lB[(slot) * 16384 + dstw + 1 * 512]), 16, 0, 0);     \
        __builtin_amdgcn_global_load_lds(AS1(gA + (size_t)16 * KD + (kt)),                         \
                                         AS3(&lA[(slot) * 16384 + dstw + 2 * 512]), 16, 0, 0);     \
        __builtin_amdgcn_global_load_lds(AS1(gB + (size_t)16 * KD + (kt)),                         \
                                         AS3(&lB[(slot) * 16384 + dstw + 2 * 512]), 16, 0, 0);     \
        __builtin_amdgcn_global_load_lds(AS1(gA + (size_t)24 * KD + (kt)),                         \
                                         AS3(&lA[(slot) * 16384 + dstw + 3 * 512]), 16, 0, 0);     \
        __builtin_amdgcn_global_load_lds(AS1(gB + (size_t)24 * KD + (kt)),                         \
                                         AS3(&lB[(slot) * 16384 + dstw + 3 * 512]), 16, 0, 0);     \
    } while (0)

#define PH(slot, ks)                                                                               \
    do {                                                                                           \
        const ushort* pa = &lA[(slot) * 16384 + rowA + oK[ks]];                                    \
        const ushort* pb = &lB[(slot) * 16384 + rowB + oK[ks]];                                    \
        bf8 b0v = *(const bf8*)(pb);                                                               \
        bf8 b1v = *(const bf8*)(pb + 2048);                                                        \
        bf8 a0v = *(const bf8*)(pa);                                                               \
        bf8 a1v = *(const bf8*)(pa + 2048);                                                        \
        bf8 a2v = *(const bf8*)(pa + 4096);                                                        \
        bf8 a3v = *(const bf8*)(pa + 6144);                                                        \
        acc[0][0] = __builtin_amdgcn_mfma_f32_32x32x16_bf16(a0v, b0v, acc[0][0], 0, 0, 0);         \
        acc[0][1] = __builtin_amdgcn_mfma_f32_32x32x16_bf16(a0v, b1v, acc[0][1], 0, 0, 0);         \
        acc[1][0] = __builtin_amdgcn_mfma_f32_32x32x16_bf16(a1v, b0v, acc[1][0], 0, 0, 0);         \
        acc[1][1] = __builtin_amdgcn_mfma_f32_32x32x16_bf16(a1v, b1v, acc[1][1], 0, 0, 0);         \
        acc[2][0] = __builtin_amdgcn_mfma_f32_32x32x16_bf16(a2v, b0v, acc[2][0], 0, 0, 0);         \
        acc[2][1] = __builtin_amdgcn_mfma_f32_32x32x16_bf16(a2v, b1v, acc[2][1], 0, 0, 0);         \
        acc[3][0] = __builtin_amdgcn_mfma_f32_32x32x16_bf16(a3v, b0v, acc[3][0], 0, 0, 0);         \
        acc[3][1] = __builtin_amdgcn_mfma_f32_32x32x16_bf16(a3v, b1v, acc[3][1], 0, 0, 0);         \
    } while (0)

    STG8(0, 0);
#pragma unroll
    for (int t = 0; t < NT - 1; ++t) {
        const int slot = t & 1;
        STG8(slot ^ 1, (t + 1) * 64);
        asm volatile("s_waitcnt vmcnt(8)" ::: "memory");
        __builtin_amdgcn_s_barrier();
        __builtin_amdgcn_sched_barrier(0);
        __builtin_amdgcn_s_setprio(1);
        PH(slot, 0); PH(slot, 1); PH(slot, 2); PH(slot, 3);
        __builtin_amdgcn_s_setprio(0);
        __builtin_amdgcn_s_barrier();
    }
    asm volatile("s_waitcnt vmcnt(0)" ::: "memory");
    __builtin_amdgcn_s_barrier();
    __builtin_amdgcn_sched_barrier(0);
    {
        const int ls = (NT - 1) & 1;
        __builtin_amdgcn_s_setprio(1);
        PH(ls, 0); PH(ls, 1); PH(ls, 2); PH(ls, 3);
        __builtin_amdgcn_s_setprio(0);
    }
#undef STG8
#undef PH
}

__device__ __forceinline__ void zero_acc8(accv (&acc)[4][2]) {
#pragma unroll
    for (int i = 0; i < 4; i++)
#pragma unroll
        for (int j = 0; j < 2; j++)
#pragma unroll
            for (int r = 0; r < 16; r++) acc[i][j][r] = 0.0f;
}

// ---------------- Win: hb = bf16(silu(featb @ Win + b_in)), KD=192 (zero-padded)
__global__ __launch_bounds__(512, 2) void k_win256(const __hip_bfloat16* __restrict__ featb,
                                                   const __hip_bfloat16* __restrict__ Wt,
                                                   const float* __restrict__ bias,
                                                   __hip_bfloat16* __restrict__ hb) {
    accv acc[4][2];
    zero_acc8(acc);
    int wg = xcd_swz(blockIdx.x, 512);
    int m0 = (wg >> 1) * 256, n0 = (wg & 1) * 256;
    int lane = threadIdx.x & 63, w = threadIdx.x >> 6, wm = w >> 2, wn = w & 3;
    mm256<FEATP_>((const ushort*)featb, (const ushort*)Wt, m0, n0, acc);
#pragma unroll
    for (int fr = 0; fr < 4; fr++)
#pragma unroll
        for (int fc = 0; fc < 2; fc++) {
            int col = n0 + 64 * wn + 32 * fc + (lane & 31);
            float bv = bias[col];
#pragma unroll
            for (int r = 0; r < 16; r++) {
                int row = m0 + 128 * wm + 32 * fr + CD_ROW(r, lane);
                hb[(size_t)row * H_ + col] = f2bf(silu_f(acc[fr][fc][r] + bv));
            }
        }
}

// ===================== FUSED TAIL: womm + LN + 3x MLP + out =====================
// One block = 128 token rows, resident end-to-end in LDS.
//  hA [128][512] bf16, chunk-swizzled: global chunk g of row r stored at LDS chunk
//     (g&56)|((g&7)^(r&7)).  128 KiB.
//  lW [512][32] bf16 W-tile (BK=32), chunk-swizzled by ((n>>1)&3).  32 KiB.
// Total LDS = 160 KiB.  W streams from L2 (1.75 MB, shared across all blocks).
// HBM: h read once, states read once, out written once.
__global__ __launch_bounds__(512, 1) void k_tail(
    const __hip_bfloat16* __restrict__ states_bf,
    const __hip_bfloat16* __restrict__ Wt_wo,
    const float* __restrict__ bo,
    const __hip_bfloat16* __restrict__ h_in,
    const float* __restrict__ ln_g,
    const float* __restrict__ ln_b,
    const __hip_bfloat16* __restrict__ Wt_mlp,
    const float* __restrict__ mlp_b,
    const __hip_bfloat16* __restrict__ Wt_out,
    const float* __restrict__ bout,
    float* __restrict__ out) {
    __shared__ __align__(1024) ushort hA[65536];   // 128 KiB
    __shared__ __align__(1024) ushort lW[16384];   // 32 KiB
    const int tid = threadIdx.x, lane = tid & 63, w = tid >> 6;
    const int wm = w >> 2, wn = w & 3;
    const int l31 = lane & 31, lh = lane >> 5;
    const int m0 = xcd_swz(blockIdx.x, 512) * 128;

    accv acc[2][4];
#pragma unroll
    for (int i = 0; i < 2; ++i)
#pragma unroll
        for (int j = 0; j < 4; ++j)
#pragma unroll
            for (int r = 0; r < 16; ++r) acc[i][j][r] = 0.0f;

    // ---- issue Wo staging (4 instrs/wave) into lW, swizzle (n>>1)&3 via source perm
    {
        const ushort* Wo_u = (const ushort*)Wt_wo;
#pragma unroll
        for (int l = 0; l < 4; ++l) {
            int rbase = w * 64 + l * 16;
            const ushort* src = Wo_u + (size_t)(rbase + (lane >> 2)) * 32
                                + (((lane & 3) ^ ((lane >> 3) & 3)) << 3);
            __builtin_amdgcn_global_load_lds(AS1(src), AS3(&lW[rbase * 32]), 16, 0, 0);
        }
    }
    // ---- S-fragments (womm A operand) straight to registers
    // rows: wm*64 + l31 (acc[0]) and wm*64 + 32 + l31 (acc[1]); row stride = 32 ushorts
    const ushort* Sp = (const ushort*)states_bf + (size_t)(m0 + wm * 64 + l31) * 32 + lh * 8;
    bf8 s00 = *(const bf8*)(Sp);
    bf8 s01 = *(const bf8*)(Sp + 16);
    bf8 s10 = *(const bf8*)(Sp + 1024);        // +32 rows  (was +2048 = +64 rows: R3 bug)
    bf8 s11 = *(const bf8*)(Sp + 1024 + 16);
    // ---- issue h staging (16 instrs/wave, 1 row each) into hA, swizzled source
    {
        const ushort* hsrc = (const ushort*)h_in + (size_t)m0 * 512;
#pragma unroll
        for (int i = 0; i < 16; ++i) {
            int row = w * 16 + i;
            const ushort* src = hsrc + (size_t)row * 512
                                + (((lane & 56) | ((lane & 7) ^ (i & 7))) << 3);
            __builtin_amdgcn_global_load_lds(AS1(src), AS3(&hA[row * 512]), 16, 0, 0);
        }
    }
    // Wo's 4 loads are within the 8 oldest vm ops -> vmcnt(16) retires them (h still in flight)
    asm volatile("s_waitcnt vmcnt(16)" ::: "memory");
    asm volatile("s_waitcnt lgkmcnt(0)" ::: "memory");
    __builtin_amdgcn_s_barrier();
    __builtin_amdgcn_sched_barrier(0);

    // ---- womm MFMA: acc = S @ Wo^T
#pragma unroll
    for (int ks = 0; ks < 2; ++ks) {
#pragma unroll
        for (int fc = 0; fc < 4; ++fc) {
            int nr = wn * 128 + fc * 32 + l31;
            int c2 = (ks * 2 + lh) ^ ((nr >> 1) & 3);
            bf8 bv_ = *(const bf8*)&lW[nr * 32 + c2 * 8];
            acc[0][fc] = __builtin_amdgcn_mfma_f32_32x32x16_bf16(ks == 0 ? s00 : s01, bv_,
                                                                 acc[0][fc], 0, 0, 0);
            acc[1][fc] = __builtin_amdgcn_mfma_f32_32x32x16_bf16(ks == 0 ? s10 : s11, bv_,
                                                                 acc[1][fc], 0, 0, 0);
        }
    }
    // wait for h panel, then tmp = h + S@Wo + bo  (scattered RMW in LDS, bf16)
    asm volatile("s_waitcnt vmcnt(0)" ::: "memory");
    asm volatile("s_waitcnt lgkmcnt(0)" ::: "memory");
    __builtin_amdgcn_s_barrier();
    __builtin_amdgcn_sched_barrier(0);
    {
        float bov[4];
#pragma unroll
        for (int fc = 0; fc < 4; ++fc) bov[fc] = bo[wn * 128 + fc * 32 + l31];
#pragma unroll
        for (int fr = 0; fr < 2; ++fr)
#pragma unroll
            for (int fc = 0; fc < 4; ++fc) {
                int c = wn * 128 + fc * 32 + l31;
                int ch = c >> 3;
#pragma unroll
                for (int r = 0; r < 16; ++r) {
                    int rl = wm * 64 + fr * 32 + CD_ROW(r, lane);
                    int idx = rl * 512 + (((ch & 56) | ((ch & 7) ^ (rl & 7))) << 3) + (c & 7);
                    hA[idx] = f2us(us2f(hA[idx]) + acc[fr][fc][r] + bov[fc]);
                }
            }
    }
    asm volatile("s_waitcnt lgkmcnt(0)" ::: "memory");
    __builtin_amdgcn_s_barrier();

    // ---- LN in-LDS: wave w handles rows w*16..+15; lane reads its natural chunk
    {
        float4 g0 = *(const float4*)(ln_g + lane * 8);
        float4 g1 = *(const float4*)(ln_g + lane * 8 + 4);
        float4 b0 = *(const float4*)(ln_b + lane * 8);
        float4 b1 = *(const float4*)(ln_b + lane * 8 + 4);
        float gg[8] = {g0.x, g0.y, g0.z, g0.w, g1.x, g1.y, g1.z, g1.w};
        float bb[8] = {b0.x, b0.y, b0.z, b0.w, b1.x, b1.y, b1.z, b1.w};
        for (int i = 0; i < 16; ++i) {
            int row = w * 16 + i;
            int sw = (lane & 56) | ((lane & 7) ^ (row & 7));
            ushort* prow = &hA[row * 512 + sw * 8];
            bf8 xv = *(const bf8*)prow;
            float x[8];
            float sm = 0.f, sq = 0.f;
#pragma unroll
            for (int j = 0; j < 8; ++j) {
                x[j] = us2f((ushort)xv[j]);
                sm += x[j];
                sq += x[j] * x[j];
            }
#pragma unroll
            for (int off = 32; off; off >>= 1) {
                sm += __shfl_xor(sm, off, 64);
                sq += __shfl_xor(sq, off, 64);
            }
            float mu = sm * (1.0f / 512.0f);
            float var = sq * (1.0f / 512.0f) - mu * mu;
            float rstd = rsqrtf(fmaxf(var, 0.0f) + 1e-5f);
            bf8 o;
#pragma unroll
            for (int j = 0; j < 8; ++j)
                o[j] = (short)f2us((x[j] - mu) * rstd * gg[j] + bb[j]);
            *(bf8*)prow = o;
        }
    }
    asm volatile("s_waitcnt lgkmcnt(0)" ::: "memory");
    __builtin_amdgcn_s_barrier();

    // ---- 3 residual MLP layers, fully in-LDS. W reg-prefetched (T14).
    for (int layer = 0; layer < 3; ++layer) {
        const ushort* Wl = (const ushort*)Wt_mlp + (size_t)layer * 262144;
        const float* bl = mlp_b + layer * 512;
        float blv[4];
#pragma unroll
        for (int fc = 0; fc < 4; ++fc) blv[fc] = bl[wn * 128 + fc * 32 + l31];
#pragma unroll
        for (int i = 0; i < 2; ++i)
#pragma unroll
            for (int j = 0; j < 4; ++j)
#pragma unroll
                for (int r = 0; r < 16; ++r) acc[i][j][r] = 0.0f;
        // prologue: stage W step 0 via regs
        {
            const ushort* ws = Wl + (size_t)tid * 512;
            bf8 w0 = *(const bf8*)(ws);
            bf8 w1 = *(const bf8*)(ws + 8);
            bf8 w2 = *(const bf8*)(ws + 16);
            bf8 w3 = *(const bf8*)(ws + 24);
            ushort* wd = &lW[tid * 32];
            int x = (tid >> 1) & 3;
            *(bf8*)&wd[(0 ^ x) * 8] = w0;
            *(bf8*)&wd[(1 ^ x) * 8] = w1;
            *(bf8*)&wd[(2 ^ x) * 8] = w2;
            *(bf8*)&wd[(3 ^ x) * 8] = w3;
        }
        asm volatile("s_waitcnt lgkmcnt(0)" ::: "memory");
        __builtin_amdgcn_s_barrier();
        for (int s = 0; s < 16; ++s) {
            bf8 n0, n1, n2, n3;
            if (s < 15) {   // prefetch next W tile into regs; lands during compute
                const ushort* ws = Wl + (size_t)tid * 512 + (s + 1) * 32;
                n0 = *(const bf8*)(ws);
                n1 = *(const bf8*)(ws + 8);
                n2 = *(const bf8*)(ws + 16);
                n3 = *(const bf8*)(ws + 24);
            }
            __builtin_amdgcn_s_setprio(1);
#pragma unroll
            for (int ks = 0; ks < 2; ++ks) {
                int ch = s * 4 + ks * 2 + lh;
                int sw = (ch & 56) | ((ch & 7) ^ (lane & 7));
                bf8 a0 = *(const bf8*)&hA[(wm * 64 + l31) * 512 + sw * 8];
                bf8 a1 = *(const bf8*)&hA[(wm * 64 + 32 + l31) * 512 + sw * 8];
#pragma unroll
                for (int fc = 0; fc < 4; ++fc) {
                    int nr = wn * 128 + fc * 32 + l31;
                    int c2 = (ks * 2 + lh) ^ ((nr >> 1) & 3);
                    bf8 bfv = *(const bf8*)&lW[nr * 32 + c2 * 8];
                    acc[0][fc] = __builtin_amdgcn_mfma_f32_32x32x16_bf16(a0, bfv, acc[0][fc], 0, 0, 0);
                    acc[1][fc] = __builtin_amdgcn_mfma_f32_32x32x16_bf16(a1, bfv, acc[1][fc], 0, 0, 0);
                }
            }
            __builtin_amdgcn_s_setprio(0);
            asm volatile("s_waitcnt lgkmcnt(0)" ::: "memory");
            __builtin_amdgcn_s_barrier();      // all reads of lW done
            if (s < 15) {
                ushort* wd = &lW[tid * 32];
                int x = (tid >> 1) & 3;
                *(bf8*)&wd[(0 ^ x) * 8] = n0;
                *(bf8*)&wd[(1 ^ x) * 8] = n1;
                *(bf8*)&wd[(2 ^ x) * 8] = n2;
                *(bf8*)&wd[(3 ^ x) * 8] = n3;
            }
            asm volatile("s_waitcnt lgkmcnt(0)" ::: "memory");
            __builtin_amdgcn_s_barrier();      // new tile visible
        }
        // epilogue: hA = hA + silu(acc + b)   (residual, in-LDS)
#pragma unroll
        for (int fr = 0; fr < 2; ++fr)
#pragma unroll
            for (int fc = 0; fc < 4; ++fc) {
                int c = wn * 128 + fc * 32 + l31;
                int ch = c >> 3;
#pragma unroll
                for (int r = 0; r < 16; ++r) {
                    int rl = wm * 64 + fr * 32 + CD_ROW(r, lane);
                    int idx = rl * 512 + (((ch & 56) | ((ch & 7) ^ (rl & 7))) << 3) + (c & 7);
                    float hv = us2f(hA[idx]);
                    hA[idx] = f2us(hv + silu_f(acc[fr][fc][r] + blv[fc]));
                }
            }
        asm volatile("s_waitcnt lgkmcnt(0)" ::: "memory");
        __builtin_amdgcn_s_barrier();
    }

    // ---- out layer: N=256, K=512, fp32 store
    {
        const ushort* Wl = (const ushort*)Wt_out;
        float bov2[2];
        bov2[0] = bout[wn * 64 + l31];
        bov2[1] = bout[wn * 64 + 32 + l31];
#pragma unroll
        for (int i = 0; i < 2; ++i)
#pragma unroll
            for (int j = 0; j < 2; ++j)
#pragma unroll
                for (int r = 0; r < 16; ++r) acc[i][j][r] = 0.0f;
        // prologue: thread t covers row t>>1, chunk pair (t&1)*2
        {
            const ushort* ws = Wl + (size_t)(tid >> 1) * 512 + (tid & 1) * 16;
            bf8 w0 = *(const bf8*)(ws);
            bf8 w1 = *(const bf8*)(ws + 8);
            ushort* wd = &lW[(tid >> 1) * 32];
            int x = (tid >> 2) & 3;
            int c0 = (tid & 1) * 2;
            *(bf8*)&wd[(c0 ^ x) * 8] = w0;
            *(bf8*)&wd[((c0 + 1) ^ x) * 8] = w1;
        }
        asm volatile("s_waitcnt lgkmcnt(0)" ::: "memory");
        __builtin_amdgcn_s_barrier();
        for (int s = 0; s < 16; ++s) {
            bf8 n0, n1;
            if (s < 15) {
                const ushort* ws = Wl + (size_t)(tid >> 1) * 512 + (s + 1) * 32 + (tid & 1) * 16;
                n0 = *(const bf8*)(ws);
                n1 = *(const bf8*)(ws + 8);
            }
            __builtin_amdgcn_s_setprio(1);
#pragma unroll
            for (int ks = 0; ks < 2; ++ks) {
                int ch = s * 4 + ks * 2 + lh;
                int sw = (ch & 56) | ((ch & 7) ^ (lane & 7));
                bf8 a0 = *(const bf8*)&hA[(wm * 64 + l31) * 512 + sw * 8];
                bf8 a1 = *(const bf8*)&hA[(wm * 64 + 32 + l31) * 512 + sw * 8];
#pragma unroll
                for (int fc = 0; fc < 2; ++fc) {
                    int nr = wn * 64 + fc * 32 + l31;
                    int c2 = (ks * 2 + lh) ^ ((nr >> 1) & 3);
                    bf8 bfv = *(const bf8*)&lW[nr * 32 + c2 * 8];
                    acc[0][fc] = __builtin_amdgcn_mfma_f32_32x32x16_bf16(a0, bfv, acc[0][fc], 0, 0, 0);
                    acc[1][fc] = __builtin_amdgcn_mfma_f32_32x32x16_bf16(a1, bfv, acc[1][fc], 0, 0, 0);
                }
            }
            __builtin_amdgcn_s_setprio(0);
            asm volatile("s_waitcnt lgkmcnt(0)" ::: "memory");
            __builtin_amdgcn_s_barrier();
            if (s < 15) {
                ushort* wd = &lW[(tid >> 1) * 32];
                int x = (tid >> 2) & 3;
                int c0 = (tid & 1) * 2;
                *(bf8*)&wd[(c0 ^ x) * 8] = n0;
                *(bf8*)&wd[((c0 + 1) ^ x) * 8] = n1;
            }
            asm volatile("s_waitcnt lgkmcnt(0)" ::: "memory");
            __builtin_amdgcn_s_barrier();
        }
        // epilogue: fp32 stores (coalesced across lane&31)
#pragma unroll
        for (int fr = 0; fr < 2; ++fr)
#pragma unroll
            for (int fc = 0; fc < 2; ++fc) {
                int col = wn * 64 + fc * 32 + l31;
#pragma unroll
                for (int r = 0; r < 16; ++r) {
                    int rl = wm * 64 + fr * 32 + CD_ROW(r, lane);
                    out[(size_t)(m0 + rl) * V_ + col] = acc[fr][fc][r] + bov2[fc];
                }
            }
    }
}

// ---------------- gates/drive: [g|i] = hb @ [Wg|Wi]; tile 256x64, K=512
__global__ __launch_bounds__(256) void k_gates_mfma(const __hip_bfloat16* __restrict__ hb,
                                                    const __hip_bfloat16* __restrict__ Wt_gd,
                                                    const float* __restrict__ bg,
                                                    const float* __restrict__ bi,
                                                    float* __restrict__ gates,
                                                    float* __restrict__ drive) {
    __shared__ __align__(16) ushort lA[256 * 32];
    __shared__ __align__(16) ushort lB[64 * 32];
    int tid = threadIdx.x, lane = tid & 63, w = tid >> 6;
    int m0 = blockIdx.x * 256;
    accv acc[2][2];
#pragma unroll
    for (int i = 0; i < 2; i++)
#pragma unroll
        for (int j = 0; j < 2; j++)
#pragma unroll
            for (int r = 0; r < 16; r++) acc[i][j][r] = 0.0f;
    const ushort* Ab = (const ushort*)hb;
    const ushort* Bb = (const ushort*)Wt_gd;
    const ushort* pa = &lA[(64 * w + (lane & 31)) * 32 + (lane >> 5) * 8];
    const ushort* pb = &lB[((lane & 31)) * 32 + (lane >> 5) * 8];
    int cb = w * 64 + lane;
    const ushort* gB = Bb + (size_t)(cb >> 2) * H_ + (cb & 3) * 8;
    for (int kt = 0; kt < H_; kt += 32) {
#pragma unroll
        for (int j = 0; j < 4; j++) {
            int c = w * 256 + j * 64 + lane;
            __builtin_amdgcn_global_load_lds(
                AS1(Ab + (size_t)(m0 + (c >> 2)) * H_ + (c & 3) * 8 + kt),
                AS3(&lA[(w * 256 + j * 64) * 8]), 16, 0, 0);
        }
        __builtin_amdgcn_global_load_lds(AS1(gB + kt), AS3(&lB[(w * 64) * 8]), 16, 0, 0);
        __syncthreads();
#pragma unroll
        for (int ks = 0; ks < 2; ks++) {
            bf8 a0 = *(const bf8*)(pa + ks * 16);
            bf8 a1 = *(const bf8*)(pa + 32 * 32 + ks * 16);
            bf8 b0 = *(const bf8*)(pb + ks * 16);
            bf8 b1 = *(const bf8*)(pb + 32 * 32 + ks * 16);
            acc[0][0] = __builtin_amdgcn_mfma_f32_32x32x16_bf16(a0, b0, acc[0][0], 0, 0, 0);
            acc[0][1] = __builtin_amdgcn_mfma_f32_32x32x16_bf16(a0, b1, acc[0][1], 0, 0, 0);
            acc[1][0] = __builtin_amdgcn_mfma_f32_32x32x16_bf16(a1, b0, acc[1][0], 0, 0, 0);
            acc[1][1] = __builtin_amdgcn_mfma_f32_32x32x16_bf16(a1, b1, acc[1][1], 0, 0, 0);
        }
        __syncthreads();
    }
    int c = lane & 31;
    float bgv = bg[c], biv = bi[c];
#pragma unroll
    for (int i = 0; i < 2; i++)
#pragma unroll
        for (int r = 0; r < 16; r++) {
            int row = m0 + 64 * w + 32 * i + CD_ROW(r, lane);
            float g = sigm_f(acc[i][0][r] + bgv);
            float d = (1.0f - g) * (acc[i][1][r] + biv);
            gates[(size_t)row * SS_ + c] = g;
            drive[(size_t)row * SS_ + c] = d;
        }
}

// ===================== weight prep: bf16 + transpose + Qtab =====================
__global__ __launch_bounds__(256) void k_prep_w(const float* __restrict__ mlp_w,
                                                const float* __restrict__ Wout,
                                                const float* __restrict__ Win,
                                                const float* __restrict__ Wg,
                                                const float* __restrict__ Wi,
                                                const float* __restrict__ Wo,
                                                const float* __restrict__ Wq,
                                                const float* __restrict__ bq,
                                                const float* __restrict__ emb_byte,
                                                __hip_bfloat16* __restrict__ Wt_mlp,
                                                __hip_bfloat16* __restrict__ Wt_out,
                                                __hip_bfloat16* __restrict__ Wt_win,
                                                __hip_bfloat16* __restrict__ Wt_gd,
                                                __hip_bfloat16* __restrict__ Wt_wo,
                                                float* __restrict__ Qtab) {
    int idx = blockIdx.x * 256 + threadIdx.x;
    if (idx < 786432) {
        int l = idx >> 18, rem = idx & 262143;
        int n = rem >> 9, k = rem & 511;
        Wt_mlp[idx] = f2bf(mlp_w[l * 262144 + k * 512 + n]);
    } else if (idx < 917504) {
        int rem = idx - 786432;
        int n = rem >> 9, k = rem & 511;
        Wt_out[rem] = f2bf(Wout[k * 256 + n]);
    } else if (idx < 1015808) {
        int rem = idx - 917504;
        int n = rem / FEATP_, k = rem % FEATP_;
        Wt_win[rem] = f2bf(k < 132 ? Win[k * 512 + n] : 0.0f);
    } else if (idx < 1048576) {
        int rem = idx - 1015808;
        int n = rem >> 9, k = rem & 511;
        Wt_gd[rem] = f2bf(n < 32 ? Wg[k * 32 + n] : Wi[k * 32 + (n - 32)]);
    } else if (idx < 1064960) {
        int rem = idx - 1048576;
        int n = rem >> 5, k = rem & 31;
        Wt_wo[rem] = f2bf(Wo[k * H_ + n]);
    } else if (idx < 1081344) {
        int rem = idx - 1064960;
        int c = rem >> 6, e = rem & 63;
        float a = bq[e];
#pragma unroll 8
        for (int k = 0; k < 64; k++) a += emb_byte[c * 64 + k] * Wq[k * 64 + e];
        Qtab[rem] = a * 0.125f;   // fold 1/sqrt(E) score scale
    }
}

// ===================== token features (Qtab-based, no matvec) =====================
__global__ __launch_bounds__(256) void k_token_feats(
    const int* __restrict__ chars, const float* __restrict__ emb_byte,
    const float* __restrict__ hash_tables, const float* __restrict__ Qtab,
    __hip_bfloat16* __restrict__ featb, float* __restrict__ hfpre) {
    int wave = threadIdx.x >> 6, lane = threadIdx.x & 63;
    int token = blockIdx.x * 4 + wave;
    int t = token & (T_ - 1);
    int b = token >> 13;
    const int* crow = chars + b * T_;
    int cv[16];
#pragma unroll
    for (int j = 0; j < 16; j++) cv[j] = (t >= j) ? crow[t - j] : 0;
    int acc = 0;
    int hidx[4];
#pragma unroll
    for (int j = 0; j < 16; j++) {
        acc += cv[j] * (1 + 256 * j);
        if (j == 1) hidx[0] = acc & 4095;
        if (j == 3) hidx[1] = acc & 4095;
        if (j == 7) hidx[2] = acc & 4095;
        if (j == 15) hidx[3] = acc & 4095;
    }
    int c0 = cv[0];
    float be = emb_byte[c0 * EB_ + lane];
    float q = Qtab[c0 * 64 + lane];
    float se[4];
#pragma unroll
    for (int s = 0; s < 4; s++) se[s] = hash_tables[(s * 4096 + hidx[s]) * E_ + lane];
    float sc[4];
#pragma unroll
    for (int s = 0; s < 4; s++) {
        float v = q * se[s];
#pragma unroll
        for (int off = 32; off; off >>= 1) v += __shfl_xor(v, off, 64);
        sc[s] = v;
    }
    float mx = fmaxf(fmaxf(sc[0], sc[1]), fmaxf(sc[2], sc[3]));
    float w0 = expf(sc[0] - mx), w1 = expf(sc[1] - mx), w2 = expf(sc[2] - mx), w3 = expf(sc[3] - mx);
    float inv = 1.0f / (w0 + w1 + w2 + w3);
    float hf = (w0 * se[0] + w1 * se[1] + w2 * se[2] + w3 * se[3]) * inv;
    featb[(size_t)token * FEATP_ + lane] = f2bf(be);
    hfpre[(size_t)token * E_ + lane] = hf;
    if (lane < 32) {
        float m = 0.0f;
        if (lane < 4) {
            int k = 1 << lane;
            m = (t >= k && c0 == cv[k]) ? 1.0f : 0.0f;
        }
        featb[(size_t)token * FEATP_ + 128 + lane] = f2bf(m);
    } else {
        featb[(size_t)token * FEATP_ + 128 + lane] = f2bf(0.0f);
    }
}

// ===================== conv -> featb[64:128] =====================
__global__ __launch_bounds__(256) void k_conv(
    const float* __restrict__ hfpre, const float* __restrict__ conv_w,
    const float* __restrict__ conv_b, __hip_bfloat16* __restrict__ featb) {
    int idx = blockIdx.x * 256 + threadIdx.x;
    int e = idx & 63;
    int bt = idx >> 6;
    int t = bt & (T_ - 1);
    float acc = conv_b[e];
#pragma unroll
    for (int k = 0; k < 4; k++) {
        int tt = t - 3 + k;
        if (tt >= 0) acc += hfpre[(size_t)(bt - 3 + k) * E_ + e] * conv_w[e * 4 + k];
    }
    featb[(size_t)bt * FEATP_ + 64 + e] = f2bf(silu_f(acc));
}

// ===================== scan chain =====================
__global__ __launch_bounds__(256) void k_chunk_ab(
    const float* __restrict__ gates, const float* __restrict__ drive,
    float* __restrict__ chA, float* __restrict__ chB) {
    int gid = blockIdx.x * 256 + threadIdx.x;
    int s = gid & 31;
    int n = (gid >> 5) & (NCH_ - 1);
    int b = gid >> 13;
    int base = (b * T_ + n * CHUNK_) * SS_ + s;
    float suml = 0.f, cum_wb = 0.f, cum_a = 1.f;
    for (int i = 0; i < CHUNK_; i++) {
        float g = gates[base + i * SS_];
        float d = drive[base + i * SS_];
        suml += logf(fmaxf(g, 1e-6f));
        cum_a = expf(suml);
        cum_wb += d / fmaxf(cum_a, 1e-8f);
    }
    chA[gid] = cum_a;
    chB[gid] = cum_a * cum_wb;
}

__global__ void k_chunk_scan(const float* __restrict__ chA, const float* __restrict__ chB,
                             float* __restrict__ chH) {
    int tid = threadIdx.x;     // 256 = B*SS
    int b = tid >> 5, s = tid & 31;
    const float* pA = chA + (size_t)b * NCH_ * SS_ + s;
    const float* pB = chB + (size_t)b * NCH_ * SS_ + s;
    float* pH = chH + (size_t)b * NCH_ * SS_ + s;
    float hc = 0.f;
    for (int n = 0; n < NCH_; n += 8) {
        float a[8], bb[8];
#pragma unroll
        for (int i = 0; i < 8; i++) {
            a[i] = pA[(n + i) * SS_];
            bb[i] = pB[(n + i) * SS_];
        }
#pragma unroll
        for (int i = 0; i < 8; i++) {
            pH[(n + i) * SS_] = hc;
            hc = a[i] * hc + bb[i];
        }
    }
}

__global__ __launch_bounds__(256) void k_states(
    const float* __restrict__ gates, const float* __restrict__ drive,
    const float* __restrict__ chH, __hip_bfloat16* __restrict__ states_bf) {
    int gid = blockIdx.x * 256 + threadIdx.x;
    int s = gid & 31;
    int n = (gid >> 5) & (NCH_ - 1);
    int b = gid >> 13;
    int base = (b * T_ + n * CHUNK_) * SS_ + s;
    float hc = chH[gid];
    float suml = 0.f, cum_wb = 0.f;
    for (int i = 0; i < CHUNK_; i++) {
        float g = gates[base + i * SS_];
        float d = drive[base + i * SS_];
        suml += logf(fmaxf(g, 1e-6f));
        float cum_a = expf(suml);
        cum_wb += d / fmaxf(cum_a, 1e-8f);
        states_bf[base + i * SS_] = f2bf(cum_a * (hc + cum_wb));
    }
}

// ===================== launch =====================
extern "C" void kernel_launch(void* const* d_in, const int* in_sizes, int n_in,
                              void* d_out, int out_size, void* d_ws, size_t ws_size,
                              hipStream_t stream) {
    (void)in_sizes; (void)n_in; (void)out_size; (void)ws_size;
    const int*   chars       = (const int*)  d_in[0];
    const float* emb_byte    = (const float*)d_in[1];
    const float* hash_tables = (const float*)d_in[2];
    const float* Wq          = (const float*)d_in[3];
    const float* bq          = (const float*)d_in[4];
    const float* conv_w      = (const float*)d_in[5];
    const float* conv_b      = (const float*)d_in[6];
    const float* Win         = (const float*)d_in[7];
    const float* b_in        = (const float*)d_in[8];
    const float* Wg          = (const float*)d_in[9];
    const float* bg          = (const float*)d_in[10];
    const float* Wi          = (const float*)d_in[11];
    const float* bi          = (const float*)d_in[12];
    const float* Wo          = (const float*)d_in[13];
    const float* bo          = (const float*)d_in[14];
    const float* ln_g        = (const float*)d_in[15];
    const float* ln_b        = (const float*)d_in[16];
    const float* mlp_w       = (const float*)d_in[17];
    const float* mlp_b       = (const float*)d_in[18];
    const float* Wout        = (const float*)d_in[19];
    const float* bout        = (const float*)d_in[20];
    float* out = (float*)d_out;

    const size_t NTOK = (size_t)B_ * T_;  // 65536
    char* p = (char*)d_ws;
    auto alloc = [&](size_t bytes) { void* r = (void*)p; p += (bytes + 255) & ~(size_t)255; return r; };
    __hip_bfloat16* featb = (__hip_bfloat16*)alloc(NTOK * FEATP_ * 2);
    float*          hfpre = (float*)alloc(NTOK * E_ * 4);
    __hip_bfloat16* hbA   = (__hip_bfloat16*)alloc(NTOK * H_ * 2);
    __hip_bfloat16* hbB   = (__hip_bfloat16*)alloc(NTOK * H_ * 2);
    float*          gates = (float*)alloc(NTOK * SS_ * 4);
    float*          drive = (float*)alloc(NTOK * SS_ * 4);
    __hip_bfloat16* states_bf = (__hip_bfloat16*)alloc(NTOK * SS_ * 2);
    float*          chA   = (float*)alloc((size_t)B_ * NCH_ * SS_ * 4);
    float*          chB   = (float*)alloc((size_t)B_ * NCH_ * SS_ * 4);
    float*          chH   = (float*)alloc((size_t)B_ * NCH_ * SS_ * 4);
    __hip_bfloat16* Wt_mlp= (__hip_bfloat16*)alloc(3 * 512 * 512 * 2);
    __hip_bfloat16* Wt_out= (__hip_bfloat16*)alloc(256 * 512 * 2);
    __hip_bfloat16* Wt_win= (__hip_bfloat16*)alloc(512 * FEATP_ * 2);
    __hip_bfloat16* Wt_gd = (__hip_bfloat16*)alloc(64 * 512 * 2);
    __hip_bfloat16* Wt_wo = (__hip_bfloat16*)alloc(512 * SS_ * 2);
    float*          Qtab  = (float*)alloc(256 * 64 * 4);

    k_prep_w<<<4224, 256, 0, stream>>>(mlp_w, Wout, Win, Wg, Wi, Wo, Wq, bq, emb_byte,
                                       Wt_mlp, Wt_out, Wt_win, Wt_gd, Wt_wo, Qtab);
    k_token_feats<<<NTOK / 4, 256, 0, stream>>>(chars, emb_byte, hash_tables, Qtab, featb, hfpre);
    k_conv<<<NTOK * E_ / 256, 256, 0, stream>>>(hfpre, conv_w, conv_b, featb);
    k_win256<<<512, 512, 0, stream>>>(featb, Wt_win, b_in, hbA);
    k_gates_mfma<<<NTOK / 256, 256, 0, stream>>>(hbA, Wt_gd, bg, bi, gates, drive);
    k_chunk_ab<<<B_ * NCH_ * SS_ / 256, 256, 0, stream>>>(gates, drive, chA, chB);
    k_chunk_scan<<<1, 256, 0, stream>>>(chA, chB, chH);
    k_states<<<B_ * NCH_ * SS_ / 256, 256, 0, stream>>>(gates, drive, chH, states_bf);
    k_tail<<<512, 512, 0, stream>>>(states_bf, Wt_wo, bo, hbA, ln_g, ln_b,
                                    Wt_mlp, mlp_b, Wt_out, bout, out);
    (void)hbB;
}